// Round 13
// baseline (1416.423 us; speedup 1.0000x reference)
//
#include <hip/hip_runtime.h>
#include <math.h>

#define BB 32
#define PP 32
#define NN 4096
#define DD 768
#define MM 4096
#define WROWS 64           // rows per update window
#define NWIN (NN / WROWS)  // 64 windows per b
#define SKC 32             // k chunk in ksim
#define KCN (DD / SKC)     // 24 k-chunks

typedef __attribute__((ext_vector_type(8))) short short8v;
typedef __attribute__((ext_vector_type(4))) short short4v;
typedef __attribute__((ext_vector_type(4))) float float4v;

__device__ __forceinline__ float wsum(float v) {
    for (int o = 32; o > 0; o >>= 1) v += __shfl_down(v, o, 64);
    return v;
}
__device__ __forceinline__ float wmax(float v) {
    for (int o = 32; o > 0; o >>= 1) v = fmaxf(v, __shfl_down(v, o, 64));
    return v;
}
__device__ __forceinline__ unsigned short f2bf(float x) {  // RNE float->bf16
    unsigned u = __float_as_uint(x);
    return (unsigned short)((u + 0x7FFFu + ((u >> 16) & 1u)) >> 16);
}
__device__ __forceinline__ float bf2f(unsigned short h) {
    return __uint_as_float((unsigned)h << 16);
}

// ---- prot -> bf16 hi/lo split + norms (iteration 0 only) -----------------
__global__ __launch_bounds__(256) void kprotcvt(const float* __restrict__ src,
                                                unsigned short* __restrict__ pH,
                                                unsigned short* __restrict__ pL,
                                                float* __restrict__ npn) {
    int bp = blockIdx.x;
    int t = threadIdx.x;
    __shared__ float red[4];
    const float* sp = src + (size_t)bp * DD;
    float sq = 0.f;
#pragma unroll
    for (int i = 0; i < 3; ++i) {
        float v = sp[t + 256 * i];
        unsigned short h = f2bf(v);
        pH[(size_t)bp * DD + t + 256 * i] = h;
        pL[(size_t)bp * DD + t + 256 * i] = f2bf(v - bf2f(h));
        sq += v * v;
    }
    float m = wsum(sq);
    int lane = t & 63, w = t >> 6;
    if (!lane) red[w] = m;
    __syncthreads();
    if (t == 0) npn[bp] = sqrtf(red[0] + red[1] + red[2] + red[3]);
}

// ---- cosine-sim GEMM via bf16 MFMA, exact 4-term hi/lo split -------------
// ZERO LDS / ZERO barriers: grid BB*16, 256 thr = 4 independent waves.
// Wave w owns n in [nt*256 + w*64, +64) x all 32 p. Fragments loaded
// global->register (lane = row l&15, k-slice (l>>4)*8), converted in-reg.
// Manual 2-chunk register double-buffer hides HBM latency under MFMA.
#define KLOAD(fS, aHS, aLS, K0)                                              \
    {                                                                        \
        _Pragma("unroll") for (int nf = 0; nf < 4; ++nf) {                   \
            const float* rp = fb + (size_t)(nf * 16 + col) * DD + (K0) + kg * 8; \
            fS[nf][0] = *(const float4*)rp;                                  \
            fS[nf][1] = *(const float4*)(rp + 4);                            \
        }                                                                    \
        _Pragma("unroll") for (int ph = 0; ph < 2; ++ph) {                   \
            size_t ao = (size_t)(ph * 16 + col) * DD + (K0) + kg * 8;        \
            aHS[ph] = *(const short8v*)&aHb[ao];                             \
            aLS[ph] = *(const short8v*)&aLb[ao];                             \
        }                                                                    \
    }

#define KCOMP(fS, aHS, aLS)                                                  \
    {                                                                        \
        _Pragma("unroll") for (int nf = 0; nf < 4; ++nf) {                   \
            float fr[8];                                                     \
            fr[0] = fS[nf][0].x; fr[1] = fS[nf][0].y;                        \
            fr[2] = fS[nf][0].z; fr[3] = fS[nf][0].w;                        \
            fr[4] = fS[nf][1].x; fr[5] = fS[nf][1].y;                        \
            fr[6] = fS[nf][1].z; fr[7] = fS[nf][1].w;                        \
            float sq = 0.f;                                                  \
            short8v bh, bl;                                                  \
            _Pragma("unroll") for (int i = 0; i < 8; ++i) {                  \
                sq += fr[i] * fr[i];                                         \
                unsigned short h = f2bf(fr[i]);                              \
                bh[i] = (short)h;                                            \
                bl[i] = (short)f2bf(fr[i] - bf2f(h));                        \
            }                                                                \
            nacc[nf] += sq;                                                  \
            _Pragma("unroll") for (int ph = 0; ph < 2; ++ph) {               \
                acc[nf][ph] = __builtin_amdgcn_mfma_f32_16x16x32_bf16(aHS[ph], bh, acc[nf][ph], 0, 0, 0); \
                acc[nf][ph] = __builtin_amdgcn_mfma_f32_16x16x32_bf16(aHS[ph], bl, acc[nf][ph], 0, 0, 0); \
                acc[nf][ph] = __builtin_amdgcn_mfma_f32_16x16x32_bf16(aLS[ph], bh, acc[nf][ph], 0, 0, 0); \
                acc[nf][ph] = __builtin_amdgcn_mfma_f32_16x16x32_bf16(aLS[ph], bl, acc[nf][ph], 0, 0, 0); \
            }                                                                \
        }                                                                    \
    }

__global__ __launch_bounds__(256) void ksim(
    const unsigned short* __restrict__ pH, const unsigned short* __restrict__ pL,
    const float* __restrict__ npn, const float* __restrict__ feats,
    size_t fsb, float* __restrict__ out) {
    int bid = blockIdx.x;
    int b = bid >> 4, nt = bid & 15;
    int tid = threadIdx.x;
    int l = tid & 63, w = tid >> 6;
    int n0 = nt * 256 + w * 64;
    int col = l & 15, kg = l >> 4;
    const float* fb = feats + (size_t)b * fsb + (size_t)n0 * DD;
    const unsigned short* aHb = pH + (size_t)b * (PP * DD);
    const unsigned short* aLb = pL + (size_t)b * (PP * DD);
    float4v acc[4][2] = {};
    float nacc[4] = {};
    float4 fA[4][2], fB[4][2];
    short8v aHA[2], aLA[2], aHB[2], aLB[2];
    KLOAD(fA, aHA, aLA, 0);
    for (int kc = 0; kc < KCN; kc += 2) {
        if (kc + 1 < KCN) KLOAD(fB, aHB, aLB, (kc + 1) * SKC);
        KCOMP(fA, aHA, aLA);
        if (kc + 2 < KCN) KLOAD(fA, aHA, aLA, (kc + 2) * SKC);
        if (kc + 1 < KCN) KCOMP(fB, aHB, aLB);
    }
    // feats-row norms: reduce over the 4 k-groups (lanes l, l^16, l^32)
    float pn2[2][4];
#pragma unroll
    for (int ph = 0; ph < 2; ++ph)
#pragma unroll
        for (int r = 0; r < 4; ++r) pn2[ph][r] = npn[b * PP + ph * 16 + kg * 4 + r];
#pragma unroll
    for (int nf = 0; nf < 4; ++nf) {
        float s = nacc[nf];
        s += __shfl_xor(s, 16, 64);
        s += __shfl_xor(s, 32, 64);
        float nfv = sqrtf(s);
#pragma unroll
        for (int ph = 0; ph < 2; ++ph)
#pragma unroll
            for (int r = 0; r < 4; ++r) {
                int p = ph * 16 + kg * 4 + r;
                float dnm = fmaxf(pn2[ph][r] * nfv, 1e-8f);
                out[(size_t)(b * PP + p) * NN + n0 + nf * 16 + col] = acc[nf][ph][r] / dnm;
            }
    }
}

// ---- fused assign: stats (density->tau, max, Z) + argmax + counting sort -
// one block per b, 1024 threads = 16 waves. EXACT round-9 weight formula —
// the per-(n,p) comparison expression expf(s/tt-xm)/Z must not be reordered
// (round-10 log-space reformulation flipped near-tie argmaxes and failed).
__global__ __launch_bounds__(1024) void kassign(const float* __restrict__ sim,
                                                int* __restrict__ sortn,
                                                float* __restrict__ sortw,
                                                int* __restrict__ cnt,
                                                int* __restrict__ offs,
                                                int hasPrev) {
    __shared__ float swv[NN];            // 16 KB weights
    __shared__ unsigned char sidx[NN];   // 4 KB argmax idx
    __shared__ int cntc[64][PP];         // 8 KB per-chunk per-p counts -> bases
    __shared__ float ttl[PP], xml[PP], zrl[PP];
    __shared__ int offp[PP], totl[PP];
    int b = blockIdx.x;
    int tid = threadIdx.x;
    int w = tid >> 6, lane = tid & 63;
    const float* sb = sim + (size_t)(b * PP) * NN;

    // phase 1: per-row stats; wave w handles rows p = w, w+16
    for (int p = w; p < PP; p += 16) {
        const float4* r4 = (const float4*)(sb + (size_t)p * NN);
        float mx = -3.4e38f;
        for (int q = 0; q < 16; ++q) {
            float4 x = r4[lane + 64 * q];
            mx = fmaxf(mx, fmaxf(fmaxf(x.x, x.y), fmaxf(x.z, x.w)));
        }
        float bm = wmax(mx);
        bm = __shfl(bm, 0, 64);
        float ttv;
        if (hasPrev) {
            int bp = b * PP + p;
            int c = cnt[bp];
            const int* lp = sortn + (size_t)b * NN + offs[bp];
            float s = 0.f;
            for (int jj = lane; jj < c; jj += 64) s += sb[(size_t)p * NN + (lp[jj] & 0xFFF)];
            float sm = wsum(s);
            sm = __shfl(sm, 0, 64);
            float density = (c >= 1) ? (1.f - sm / (float)c) : 1.f;
            ttv = 0.1f * fmaxf(density, 1e-10f);
        } else {
            ttv = 0.01f;  // TEMP * TAU0
        }
        float xm = bm / ttv;
        float z = 0.f;
        for (int q = 0; q < 16; ++q) {
            float4 x = r4[lane + 64 * q];
            z += expf(x.x / ttv - xm) + expf(x.y / ttv - xm) +
                 expf(x.z / ttv - xm) + expf(x.w / ttv - xm);
        }
        float zz = wsum(z);
        if (lane == 0) { ttl[p] = ttv; xml[p] = xm; zrl[p] = zz; }
    }
    __syncthreads();

    // phase 2: per-n argmax + per-chunk counts (exact round-9 arithmetic)
    for (int ci = 0; ci < 4; ++ci) {
        int c = w + 16 * ci;
        int n = c * 64 + lane;
        float best = -1.f;
        int bi = 0;
#pragma unroll
        for (int p = 0; p < PP; ++p) {
            float s = sb[(size_t)p * NN + n];
            float wgt = expf(s / ttl[p] - xml[p]) / zrl[p];
            if (wgt > best) { best = wgt; bi = p; }
        }
        sidx[n] = (unsigned char)bi;
        swv[n] = best;
#pragma unroll
        for (int p = 0; p < PP; ++p) {
            unsigned long long bal = __ballot(bi == p);
            if (lane == p) cntc[c][p] = __popcll(bal);
        }
    }
    __syncthreads();

    // phase 3: per-p prefix over chunks, then exclusive prefix over p
    if (tid < PP) {
        int run = 0;
        for (int c = 0; c < 64; ++c) {
            int t_ = cntc[c][tid];
            cntc[c][tid] = run;
            run += t_;
        }
        totl[tid] = run;
        cnt[b * PP + tid] = run;
    }
    __syncthreads();
    if (tid == 0) {
        int s = 0;
        for (int p = 0; p < PP; ++p) {
            offp[p] = s;
            offs[b * PP + p] = s;
            s += totl[p];
        }
    }
    __syncthreads();

    // phase 4: stable scatter (ascending n within bucket)
    for (int ci = 0; ci < 4; ++ci) {
        int c = w + 16 * ci;
        int n = c * 64 + lane;
        int bi = sidx[n];
        float wgt = swv[n];
        unsigned long long below = (1ull << lane) - 1ull;
#pragma unroll
        for (int p = 0; p < PP; ++p) {
            unsigned long long bal = __ballot(bi == p);
            if (bi == p) {
                int rank = __popcll(bal & below);
                int pos = offp[p] + cntc[c][p] + rank;
                sortn[(size_t)b * NN + pos] = (p << 12) | n;
                sortw[(size_t)b * NN + pos] = wgt;
            }
        }
    }
}

// ---- update: 64-row window, float4 gather with 4-deep register prefetch --
#define UPD_STEP(FREG, JIDX, NXT)                                          \
    {                                                                      \
        int e = sn[JIDX];                                                  \
        int p = e >> 12;                                                   \
        float wv = sw[JIDX];                                               \
        float4 f = FREG;                                                   \
        if ((NXT) < WROWS) FREG = fb[(size_t)(sn[NXT] & 0xFFF) * 192 + t]; \
        if (p != curp) {                                                   \
            float4 o = {ax, ay, az, aw};                                   \
            pw[(size_t)curp * 192 + t] = o;                                \
            ax = ay = az = aw = 0.f;                                       \
            curp = p;                                                      \
        }                                                                  \
        ax = fmaf(wv, f.x, ax);                                            \
        ay = fmaf(wv, f.y, ay);                                            \
        az = fmaf(wv, f.z, az);                                            \
        aw = fmaf(wv, f.w, aw);                                            \
    }

__global__ __launch_bounds__(192) void kupdate(const float* __restrict__ feats,
                                               const int* __restrict__ sortn,
                                               const float* __restrict__ sortw,
                                               float* __restrict__ part) {
    __shared__ int sn[WROWS];
    __shared__ float sw[WROWS];
    int win = blockIdx.x & (NWIN - 1);
    int b = blockIdx.x >> 6;
    int t = threadIdx.x;
    if (t < WROWS) {
        sn[t] = sortn[b * NN + win * WROWS + t];
        sw[t] = sortw[b * NN + win * WROWS + t];
    }
    __syncthreads();
    const float4* fb = (const float4*)(feats + (size_t)b * NN * DD);
    float4* pw = (float4*)(part + (size_t)(b * NWIN + win) * PP * DD);
    float ax = 0.f, ay = 0.f, az = 0.f, aw = 0.f;
    int curp = sn[0] >> 12;
    float4 fp0 = fb[(size_t)(sn[0] & 0xFFF) * 192 + t];
    float4 fp1 = fb[(size_t)(sn[1] & 0xFFF) * 192 + t];
    float4 fp2 = fb[(size_t)(sn[2] & 0xFFF) * 192 + t];
    float4 fp3 = fb[(size_t)(sn[3] & 0xFFF) * 192 + t];
    for (int jj = 0; jj < WROWS; jj += 4) {
        UPD_STEP(fp0, jj + 0, jj + 4);
        UPD_STEP(fp1, jj + 1, jj + 5);
        UPD_STEP(fp2, jj + 2, jj + 6);
        UPD_STEP(fp3, jj + 3, jj + 7);
    }
    float4 o = {ax, ay, az, aw};
    pw[(size_t)curp * 192 + t] = o;
}

// ---- reduce window partials -> prot bf16 hi/lo + npn (+ final out) -------
__global__ __launch_bounds__(192) void kreduce(const float* __restrict__ part,
                                               const int* __restrict__ offs,
                                               const int* __restrict__ cnt,
                                               unsigned short* __restrict__ pH,
                                               unsigned short* __restrict__ pL,
                                               float* __restrict__ npn,
                                               float* __restrict__ outp) {
    int bp = blockIdx.x;
    int b = bp >> 5, p = bp & 31;
    int t = threadIdx.x;
    __shared__ float red[3];
    float4 s = {0.f, 0.f, 0.f, 0.f};
    int c = cnt[bp];
    if (c > 0) {
        int j0 = offs[bp];
        int w0 = j0 >> 6, w1 = (j0 + c - 1) >> 6;
        const float4* pr = (const float4*)(part);
        for (int w = w0; w <= w1; ++w) {
            float4 v = pr[(size_t)((b * NWIN + w) * PP + p) * 192 + t];
            s.x += v.x; s.y += v.y; s.z += v.z; s.w += v.w;
        }
    }
    if (outp) ((float4*)(outp + (size_t)bp * DD))[t] = s;
    short4v hv, lv;
    unsigned short h;
    h = f2bf(s.x); hv.x = (short)h; lv.x = (short)f2bf(s.x - bf2f(h));
    h = f2bf(s.y); hv.y = (short)h; lv.y = (short)f2bf(s.y - bf2f(h));
    h = f2bf(s.z); hv.z = (short)h; lv.z = (short)f2bf(s.z - bf2f(h));
    h = f2bf(s.w); hv.w = (short)h; lv.w = (short)f2bf(s.w - bf2f(h));
    *(short4v*)&pH[(size_t)bp * DD + 4 * t] = hv;
    *(short4v*)&pL[(size_t)bp * DD + 4 * t] = lv;
    float sq = s.x * s.x + s.y * s.y + s.z * s.z + s.w * s.w;
    float m = wsum(sq);
    int lane = t & 63, w = t >> 6;
    if (!lane) red[w] = m;
    __syncthreads();
    if (t == 0) npn[bp] = sqrtf(red[0] + red[1] + red[2]);
}

extern "C" void kernel_launch(void* const* d_in, const int* in_sizes, int n_in,
                              void* d_out, int out_size, void* d_ws, size_t ws_size,
                              hipStream_t stream) {
    const float* protIn = (const float*)d_in[0];
    const float* feats = (const float*)d_in[1];
    const float* forg = (const float*)d_in[2];
    float* out = (float*)d_out;

    char* w = (char*)d_ws;
    auto alloc = [&](size_t bytes) {
        char* p = w;
        w += (bytes + 255) & ~(size_t)255;
        return p;
    };
    float* sim = (float*)alloc((size_t)BB * PP * NN * 4);
    float* part = (float*)alloc((size_t)BB * NWIN * PP * DD * 4);
    unsigned short* pH = (unsigned short*)alloc((size_t)BB * PP * DD * 2);
    unsigned short* pL = (unsigned short*)alloc((size_t)BB * PP * DD * 2);
    float* npn = (float*)alloc(BB * PP * 4);
    int* sortn = (int*)alloc((size_t)BB * NN * 4);
    float* sortw = (float*)alloc((size_t)BB * NN * 4);
    int* cnt = (int*)alloc(BB * PP * 4);
    int* offs = (int*)alloc(BB * PP * 4);

    kprotcvt<<<BB * PP, 256, 0, stream>>>(protIn, pH, pL, npn);
    for (int t = 0; t < 5; ++t) {
        ksim<<<BB * 16, 256, 0, stream>>>(pH, pL, npn, feats, (size_t)NN * DD, sim);
        kassign<<<BB, 1024, 0, stream>>>(sim, sortn, sortw, cnt, offs, t > 0 ? 1 : 0);
        kupdate<<<BB * NWIN, 192, 0, stream>>>(feats, sortn, sortw, part);
        kreduce<<<BB * PP, 192, 0, stream>>>(part, offs, cnt, pH, pL, npn,
                                             (t == 4) ? out : nullptr);
    }
    // final similarity against feats_org (broadcast fsb=0) -> second output
    ksim<<<BB * 16, 256, 0, stream>>>(pH, pL, npn, forg, (size_t)0,
                                      out + (size_t)BB * PP * DD);
}

// Round 14
// 1363.194 us; speedup vs baseline: 1.0390x; 1.0390x over previous
//
#include <hip/hip_runtime.h>
#include <math.h>

#define BB 32
#define PP 32
#define NN 4096
#define DD 768
#define MM 4096
#define WROWS 64           // rows per update window
#define NWIN (NN / WROWS)  // 64 windows per b
#define SIMB 128           // n per ksim block
#define SNT (NN / SIMB)    // 32 n-tiles
#define SKC 32             // k chunk in ksim
#define KCN (DD / SKC)     // 24 k-chunks
#define FPAD 40            // shorts per LDS row (32 + 8 pad)

typedef __attribute__((ext_vector_type(8))) short short8v;
typedef __attribute__((ext_vector_type(4))) short short4v;
typedef __attribute__((ext_vector_type(4))) float float4v;

__device__ __forceinline__ float wsum(float v) {
    for (int o = 32; o > 0; o >>= 1) v += __shfl_down(v, o, 64);
    return v;
}
__device__ __forceinline__ float wmax(float v) {
    for (int o = 32; o > 0; o >>= 1) v = fmaxf(v, __shfl_down(v, o, 64));
    return v;
}
__device__ __forceinline__ unsigned short f2bf(float x) {  // RNE float->bf16
    unsigned u = __float_as_uint(x);
    return (unsigned short)((u + 0x7FFFu + ((u >> 16) & 1u)) >> 16);
}
__device__ __forceinline__ float bf2f(unsigned short h) {
    return __uint_as_float((unsigned)h << 16);
}

// ---- cosine-sim GEMM via bf16 MFMA, exact 4-term hi/lo split -------------
// grid: BB*SNT blocks, 256 threads (4 waves); wave tile 16p x 64n.
// Conversion hoisted OUT of the barrier-locked region (runs during MFMA of
// the previous chunk); 2-chunk register prefetch covers HBM latency.
#define KSIM_LOAD(FV, PV, K0)                                                \
    {                                                                        \
        _Pragma("unroll") for (int ps = 0; ps < 4; ++ps)                     \
            FV[ps] = *(const float4*)&fb[(size_t)(row + 32 * ps) * DD + (K0) + j * 4]; \
        PV = *(const float4*)&pb[(size_t)row * DD + (K0) + j * 4];           \
    }

#define CVT1(VV, HH, LL)                                                     \
    {                                                                        \
        unsigned short h_;                                                   \
        h_ = f2bf(VV.x); HH.x = (short)h_; LL.x = (short)f2bf(VV.x - bf2f(h_)); \
        h_ = f2bf(VV.y); HH.y = (short)h_; LL.y = (short)f2bf(VV.y - bf2f(h_)); \
        h_ = f2bf(VV.z); HH.z = (short)h_; LL.z = (short)f2bf(VV.z - bf2f(h_)); \
        h_ = f2bf(VV.w); HH.w = (short)h_; LL.w = (short)f2bf(VV.w - bf2f(h_)); \
    }

#define KSIM_CONV(FV, PV, FH, FL, PHv, PLv)                                  \
    {                                                                        \
        _Pragma("unroll") for (int ps = 0; ps < 4; ++ps) {                   \
            float4 v = FV[ps];                                               \
            nacc[ps] += v.x * v.x + v.y * v.y + v.z * v.z + v.w * v.w;       \
            CVT1(v, FH[ps], FL[ps]);                                         \
        }                                                                    \
        {                                                                    \
            float4 v = PV;                                                   \
            pacc += v.x * v.x + v.y * v.y + v.z * v.z + v.w * v.w;           \
            CVT1(v, PHv, PLv);                                               \
        }                                                                    \
    }

#define KSIM_STAGE(FH, FL, PHv, PLv)                                         \
    {                                                                        \
        _Pragma("unroll") for (int ps = 0; ps < 4; ++ps) {                   \
            *(short4v*)&fsH[row + 32 * ps][j * 4] = FH[ps];                  \
            *(short4v*)&fsL[row + 32 * ps][j * 4] = FL[ps];                  \
        }                                                                    \
        *(short4v*)&psH[row][j * 4] = PHv;                                   \
        *(short4v*)&psL[row][j * 4] = PLv;                                   \
    }

#define KSIM_MFMA()                                                          \
    {                                                                        \
        short8v ah = *(const short8v*)&psH[wp * 16 + (l & 15)][(l >> 4) * 8]; \
        short8v al = *(const short8v*)&psL[wp * 16 + (l & 15)][(l >> 4) * 8]; \
        _Pragma("unroll") for (int nf = 0; nf < 4; ++nf) {                   \
            int nr = wn * 64 + nf * 16 + (l & 15);                           \
            short8v bh = *(const short8v*)&fsH[nr][(l >> 4) * 8];            \
            short8v bl = *(const short8v*)&fsL[nr][(l >> 4) * 8];            \
            acc[nf] = __builtin_amdgcn_mfma_f32_16x16x32_bf16(ah, bh, acc[nf], 0, 0, 0); \
            acc[nf] = __builtin_amdgcn_mfma_f32_16x16x32_bf16(ah, bl, acc[nf], 0, 0, 0); \
            acc[nf] = __builtin_amdgcn_mfma_f32_16x16x32_bf16(al, bh, acc[nf], 0, 0, 0); \
            acc[nf] = __builtin_amdgcn_mfma_f32_16x16x32_bf16(al, bl, acc[nf], 0, 0, 0); \
        }                                                                    \
    }

__global__ __launch_bounds__(256) void ksim(
    const float* __restrict__ prot, const float* __restrict__ feats,
    size_t fsb, float* __restrict__ out) {
    __shared__ short fsH[SIMB][FPAD];
    __shared__ short fsL[SIMB][FPAD];
    __shared__ short psH[PP][FPAD];
    __shared__ short psL[PP][FPAD];
    __shared__ float nfl[SIMB];
    __shared__ float pnl[PP];
    int bid = blockIdx.x;
    int b = bid >> 5, nt = bid & 31;
    int n0 = nt * SIMB;
    int tid = threadIdx.x;
    int row = tid >> 3, j = tid & 7;
    int l = tid & 63, w = tid >> 6;
    int wp = w & 1, wn = w >> 1;
    const float* fb = feats + (size_t)b * fsb + (size_t)n0 * DD;
    const float* pb = prot + (size_t)b * (PP * DD);
    float4v acc[4] = {};
    float nacc[4] = {};
    float pacc = 0.f;
    float4 fvA[4], pvA, fvB[4], pvB;
    short4v fhA[4], flA[4], phA, plA, fhB[4], flB[4], phB, plB;
    KSIM_LOAD(fvA, pvA, 0);
    KSIM_LOAD(fvB, pvB, SKC);
    KSIM_CONV(fvA, pvA, fhA, flA, phA, plA);
    for (int kc = 0; kc < KCN; kc += 2) {
        __builtin_amdgcn_s_barrier();  // LDS free (prev MFMA done)
        asm volatile("" ::: "memory");
        KSIM_STAGE(fhA, flA, phA, plA);
        asm volatile("s_waitcnt lgkmcnt(0)" ::: "memory");
        __builtin_amdgcn_s_barrier();  // staged visible
        asm volatile("" ::: "memory");
        if (kc + 1 < KCN) KSIM_CONV(fvB, pvB, fhB, flB, phB, plB);
        if (kc + 2 < KCN) KSIM_LOAD(fvA, pvA, (kc + 2) * SKC);
        KSIM_MFMA();
        if (kc + 1 < KCN) {
            __builtin_amdgcn_s_barrier();
            asm volatile("" ::: "memory");
            KSIM_STAGE(fhB, flB, phB, plB);
            asm volatile("s_waitcnt lgkmcnt(0)" ::: "memory");
            __builtin_amdgcn_s_barrier();
            asm volatile("" ::: "memory");
            if (kc + 2 < KCN) KSIM_CONV(fvA, pvA, fhA, flA, phA, plA);
            if (kc + 3 < KCN) KSIM_LOAD(fvB, pvB, (kc + 3) * SKC);
            KSIM_MFMA();
        }
    }
    // norm reductions over 8-lane j-groups
#pragma unroll
    for (int ps = 0; ps < 4; ++ps) {
        float s = nacc[ps];
        s += __shfl_xor(s, 1, 64);
        s += __shfl_xor(s, 2, 64);
        s += __shfl_xor(s, 4, 64);
        if (j == 0) nfl[row + 32 * ps] = sqrtf(s);
    }
    {
        float s = pacc;
        s += __shfl_xor(s, 1, 64);
        s += __shfl_xor(s, 2, 64);
        s += __shfl_xor(s, 4, 64);
        if (j == 0) pnl[row] = sqrtf(s);
    }
    __syncthreads();
#pragma unroll
    for (int nf = 0; nf < 4; ++nf) {
        int nr = wn * 64 + nf * 16 + (l & 15);
        float fn = nfl[nr];
#pragma unroll
        for (int r = 0; r < 4; ++r) {
            int p = wp * 16 + (l >> 4) * 4 + r;
            float dnm = fmaxf(pnl[p] * fn, 1e-8f);
            out[(size_t)(b * PP + p) * NN + n0 + nr] = acc[nf][r] / dnm;
        }
    }
}

// ---- fused assign: stats (density->tau, max, Z) + argmax + counting sort -
// one block per b, 1024 threads = 16 waves. EXACT round-9 weight formula —
// the per-(n,p) comparison expression expf(s/tt-xm)/Z must not be reordered
// (round-10 log-space reformulation flipped near-tie argmaxes and failed).
__global__ __launch_bounds__(1024) void kassign(const float* __restrict__ sim,
                                                int* __restrict__ sortn,
                                                float* __restrict__ sortw,
                                                int* __restrict__ cnt,
                                                int* __restrict__ offs,
                                                int hasPrev) {
    __shared__ float swv[NN];            // 16 KB weights
    __shared__ unsigned char sidx[NN];   // 4 KB argmax idx
    __shared__ int cntc[64][PP];         // 8 KB per-chunk per-p counts -> bases
    __shared__ float ttl[PP], xml[PP], zrl[PP];
    __shared__ int offp[PP], totl[PP];
    int b = blockIdx.x;
    int tid = threadIdx.x;
    int w = tid >> 6, lane = tid & 63;
    const float* sb = sim + (size_t)(b * PP) * NN;

    // phase 1: per-row stats; wave w handles rows p = w, w+16
    for (int p = w; p < PP; p += 16) {
        const float4* r4 = (const float4*)(sb + (size_t)p * NN);
        float mx = -3.4e38f;
        for (int q = 0; q < 16; ++q) {
            float4 x = r4[lane + 64 * q];
            mx = fmaxf(mx, fmaxf(fmaxf(x.x, x.y), fmaxf(x.z, x.w)));
        }
        float bm = wmax(mx);
        bm = __shfl(bm, 0, 64);
        float ttv;
        if (hasPrev) {
            int bp = b * PP + p;
            int c = cnt[bp];
            const int* lp = sortn + (size_t)b * NN + offs[bp];
            float s = 0.f;
            for (int jj = lane; jj < c; jj += 64) s += sb[(size_t)p * NN + (lp[jj] & 0xFFF)];
            float sm = wsum(s);
            sm = __shfl(sm, 0, 64);
            float density = (c >= 1) ? (1.f - sm / (float)c) : 1.f;
            ttv = 0.1f * fmaxf(density, 1e-10f);
        } else {
            ttv = 0.01f;  // TEMP * TAU0
        }
        float xm = bm / ttv;
        float z = 0.f;
        for (int q = 0; q < 16; ++q) {
            float4 x = r4[lane + 64 * q];
            z += expf(x.x / ttv - xm) + expf(x.y / ttv - xm) +
                 expf(x.z / ttv - xm) + expf(x.w / ttv - xm);
        }
        float zz = wsum(z);
        if (lane == 0) { ttl[p] = ttv; xml[p] = xm; zrl[p] = zz; }
    }
    __syncthreads();

    // phase 2: per-n argmax + per-chunk counts (exact round-9 arithmetic)
    for (int ci = 0; ci < 4; ++ci) {
        int c = w + 16 * ci;
        int n = c * 64 + lane;
        float best = -1.f;
        int bi = 0;
#pragma unroll
        for (int p = 0; p < PP; ++p) {
            float s = sb[(size_t)p * NN + n];
            float wgt = expf(s / ttl[p] - xml[p]) / zrl[p];
            if (wgt > best) { best = wgt; bi = p; }
        }
        sidx[n] = (unsigned char)bi;
        swv[n] = best;
#pragma unroll
        for (int p = 0; p < PP; ++p) {
            unsigned long long bal = __ballot(bi == p);
            if (lane == p) cntc[c][p] = __popcll(bal);
        }
    }
    __syncthreads();

    // phase 3: per-p prefix over chunks, then exclusive prefix over p
    if (tid < PP) {
        int run = 0;
        for (int c = 0; c < 64; ++c) {
            int t_ = cntc[c][tid];
            cntc[c][tid] = run;
            run += t_;
        }
        totl[tid] = run;
        cnt[b * PP + tid] = run;
    }
    __syncthreads();
    if (tid == 0) {
        int s = 0;
        for (int p = 0; p < PP; ++p) {
            offp[p] = s;
            offs[b * PP + p] = s;
            s += totl[p];
        }
    }
    __syncthreads();

    // phase 4: stable scatter (ascending n within bucket)
    for (int ci = 0; ci < 4; ++ci) {
        int c = w + 16 * ci;
        int n = c * 64 + lane;
        int bi = sidx[n];
        float wgt = swv[n];
        unsigned long long below = (1ull << lane) - 1ull;
#pragma unroll
        for (int p = 0; p < PP; ++p) {
            unsigned long long bal = __ballot(bi == p);
            if (bi == p) {
                int rank = __popcll(bal & below);
                int pos = offp[p] + cntc[c][p] + rank;
                sortn[(size_t)b * NN + pos] = (p << 12) | n;
                sortw[(size_t)b * NN + pos] = wgt;
            }
        }
    }
}

// ---- update: 64-row window, float4 gather with 4-deep register prefetch --
#define UPD_STEP(FREG, JIDX, NXT)                                          \
    {                                                                      \
        int e = sn[JIDX];                                                  \
        int p = e >> 12;                                                   \
        float wv = sw[JIDX];                                               \
        float4 f = FREG;                                                   \
        if ((NXT) < WROWS) FREG = fb[(size_t)(sn[NXT] & 0xFFF) * 192 + t]; \
        if (p != curp) {                                                   \
            float4 o = {ax, ay, az, aw};                                   \
            pw[(size_t)curp * 192 + t] = o;                                \
            ax = ay = az = aw = 0.f;                                       \
            curp = p;                                                      \
        }                                                                  \
        ax = fmaf(wv, f.x, ax);                                            \
        ay = fmaf(wv, f.y, ay);                                            \
        az = fmaf(wv, f.z, az);                                            \
        aw = fmaf(wv, f.w, aw);                                            \
    }

__global__ __launch_bounds__(192) void kupdate(const float* __restrict__ feats,
                                               const int* __restrict__ sortn,
                                               const float* __restrict__ sortw,
                                               float* __restrict__ part) {
    __shared__ int sn[WROWS];
    __shared__ float sw[WROWS];
    int win = blockIdx.x & (NWIN - 1);
    int b = blockIdx.x >> 6;
    int t = threadIdx.x;
    if (t < WROWS) {
        sn[t] = sortn[b * NN + win * WROWS + t];
        sw[t] = sortw[b * NN + win * WROWS + t];
    }
    __syncthreads();
    const float4* fb = (const float4*)(feats + (size_t)b * NN * DD);
    float4* pw = (float4*)(part + (size_t)(b * NWIN + win) * PP * DD);
    float ax = 0.f, ay = 0.f, az = 0.f, aw = 0.f;
    int curp = sn[0] >> 12;
    float4 fp0 = fb[(size_t)(sn[0] & 0xFFF) * 192 + t];
    float4 fp1 = fb[(size_t)(sn[1] & 0xFFF) * 192 + t];
    float4 fp2 = fb[(size_t)(sn[2] & 0xFFF) * 192 + t];
    float4 fp3 = fb[(size_t)(sn[3] & 0xFFF) * 192 + t];
    for (int jj = 0; jj < WROWS; jj += 4) {
        UPD_STEP(fp0, jj + 0, jj + 4);
        UPD_STEP(fp1, jj + 1, jj + 5);
        UPD_STEP(fp2, jj + 2, jj + 6);
        UPD_STEP(fp3, jj + 3, jj + 7);
    }
    float4 o = {ax, ay, az, aw};
    pw[(size_t)curp * 192 + t] = o;
}

// ---- reduce window partials -> prototypes (+ final out) ------------------
__global__ __launch_bounds__(192) void kreduce(const float* __restrict__ part,
                                               const int* __restrict__ offs,
                                               const int* __restrict__ cnt,
                                               float* __restrict__ prot,
                                               float* __restrict__ outp) {
    int bp = blockIdx.x;
    int b = bp >> 5, p = bp & 31;
    int t = threadIdx.x;
    float4 s = {0.f, 0.f, 0.f, 0.f};
    int c = cnt[bp];
    if (c > 0) {
        int j0 = offs[bp];
        int w0 = j0 >> 6, w1 = (j0 + c - 1) >> 6;
        const float4* pr = (const float4*)(part);
        for (int w = w0; w <= w1; ++w) {
            float4 v = pr[(size_t)((b * NWIN + w) * PP + p) * 192 + t];
            s.x += v.x; s.y += v.y; s.z += v.z; s.w += v.w;
        }
    }
    ((float4*)(prot + (size_t)bp * DD))[t] = s;
    if (outp) ((float4*)(outp + (size_t)bp * DD))[t] = s;
}

extern "C" void kernel_launch(void* const* d_in, const int* in_sizes, int n_in,
                              void* d_out, int out_size, void* d_ws, size_t ws_size,
                              hipStream_t stream) {
    const float* protIn = (const float*)d_in[0];
    const float* feats = (const float*)d_in[1];
    const float* forg = (const float*)d_in[2];
    float* out = (float*)d_out;

    char* w = (char*)d_ws;
    auto alloc = [&](size_t bytes) {
        char* p = w;
        w += (bytes + 255) & ~(size_t)255;
        return p;
    };
    float* sim = (float*)alloc((size_t)BB * PP * NN * 4);
    float* prot = (float*)alloc((size_t)BB * PP * DD * 4);
    float* part = (float*)alloc((size_t)BB * NWIN * PP * DD * 4);
    int* sortn = (int*)alloc((size_t)BB * NN * 4);
    float* sortw = (float*)alloc((size_t)BB * NN * 4);
    int* cnt = (int*)alloc(BB * PP * 4);
    int* offs = (int*)alloc(BB * PP * 4);

    for (int t = 0; t < 5; ++t) {
        ksim<<<BB * SNT, 256, 0, stream>>>(t == 0 ? protIn : prot, feats,
                                           (size_t)NN * DD, sim);
        kassign<<<BB, 1024, 0, stream>>>(sim, sortn, sortw, cnt, offs, t > 0 ? 1 : 0);
        kupdate<<<BB * NWIN, 192, 0, stream>>>(feats, sortn, sortw, part);
        kreduce<<<BB * PP, 192, 0, stream>>>(part, offs, cnt, prot,
                                             (t == 4) ? out : nullptr);
    }
    // final similarity against feats_org (broadcast fsb=0) -> second output
    ksim<<<BB * SNT, 256, 0, stream>>>(prot, forg, (size_t)0,
                                       out + (size_t)BB * PP * DD);
}

// Round 15
// 1268.436 us; speedup vs baseline: 1.1167x; 1.0747x over previous
//
#include <hip/hip_runtime.h>
#include <math.h>

#define BB 32
#define PP 32
#define NN 4096
#define DD 768
#define MM 4096
#define WROWS 64           // rows per update window
#define NWIN (NN / WROWS)  // 64 windows per b
#define SIMB 128           // n per ksim block
#define SNT (NN / SIMB)    // 32 n-tiles
#define SKC 32             // k chunk in ksim
#define KCN (DD / SKC)     // 24 k-chunks
#define FPAD 40            // shorts per LDS row (32 + 8 pad)

typedef __attribute__((ext_vector_type(8))) short short8v;
typedef __attribute__((ext_vector_type(4))) short short4v;
typedef __attribute__((ext_vector_type(4))) float float4v;

__device__ __forceinline__ float wsum(float v) {
    for (int o = 32; o > 0; o >>= 1) v += __shfl_down(v, o, 64);
    return v;
}
__device__ __forceinline__ float wmax(float v) {
    for (int o = 32; o > 0; o >>= 1) v = fmaxf(v, __shfl_down(v, o, 64));
    return v;
}
__device__ __forceinline__ unsigned short f2bf(float x) {  // RNE float->bf16
    unsigned u = __float_as_uint(x);
    return (unsigned short)((u + 0x7FFFu + ((u >> 16) & 1u)) >> 16);
}
__device__ __forceinline__ float bf2f(unsigned short h) {
    return __uint_as_float((unsigned)h << 16);
}

// ---- cosine-sim GEMM via bf16 MFMA, exact 4-term hi/lo split -------------
// grid: BB*SNT blocks, 256 threads (4 waves); wave tile 16p x 64n.
// Round-9/12 structure (proven): raw-barrier pipeline, prefetch kc+1 in
// flight across MFMA + barriers. Do not restructure — reg-direct (r13),
// conversion-hoist (r14), tile changes (r4, r12) were all neutral/worse.
__global__ __launch_bounds__(256) void ksim(
    const float* __restrict__ prot, const float* __restrict__ feats,
    size_t fsb, float* __restrict__ out) {
    __shared__ short fsH[SIMB][FPAD];
    __shared__ short fsL[SIMB][FPAD];
    __shared__ short psH[PP][FPAD];
    __shared__ short psL[PP][FPAD];
    __shared__ float nfl[SIMB];
    __shared__ float pnl[PP];
    int bid = blockIdx.x;
    int b = bid >> 5, nt = bid & 31;
    int n0 = nt * SIMB;
    int tid = threadIdx.x;
    int row = tid >> 3, j = tid & 7;  // 8 threads per row (32 rows/pass)
    int l = tid & 63, w = tid >> 6;
    int wp = w & 1, wn = w >> 1;      // wave tile: 16p x 64n
    const float* fb = feats + (size_t)b * fsb + (size_t)n0 * DD;
    const float* pb = prot + (size_t)b * (PP * DD);
    float4v acc[4] = {};
    float nacc[4] = {};
    float pacc = 0.f;
    float4 fv[4], pv;
#pragma unroll
    for (int ps = 0; ps < 4; ++ps)
        fv[ps] = *(const float4*)&fb[(size_t)(row + 32 * ps) * DD + j * 4];
    pv = *(const float4*)&pb[(size_t)row * DD + j * 4];
    for (int kc = 0; kc < KCN; ++kc) {
        __builtin_amdgcn_s_barrier();  // all waves done reading LDS
        asm volatile("" ::: "memory");
#pragma unroll
        for (int ps = 0; ps < 4; ++ps) {
            float4 v = fv[ps];
            nacc[ps] += v.x * v.x + v.y * v.y + v.z * v.z + v.w * v.w;
            short4v h, lo;
            h.x = (short)f2bf(v.x); h.y = (short)f2bf(v.y);
            h.z = (short)f2bf(v.z); h.w = (short)f2bf(v.w);
            lo.x = (short)f2bf(v.x - bf2f((unsigned short)h.x));
            lo.y = (short)f2bf(v.y - bf2f((unsigned short)h.y));
            lo.z = (short)f2bf(v.z - bf2f((unsigned short)h.z));
            lo.w = (short)f2bf(v.w - bf2f((unsigned short)h.w));
            *(short4v*)&fsH[row + 32 * ps][j * 4] = h;
            *(short4v*)&fsL[row + 32 * ps][j * 4] = lo;
        }
        {
            float4 v = pv;
            pacc += v.x * v.x + v.y * v.y + v.z * v.z + v.w * v.w;
            short4v h, lo;
            h.x = (short)f2bf(v.x); h.y = (short)f2bf(v.y);
            h.z = (short)f2bf(v.z); h.w = (short)f2bf(v.w);
            lo.x = (short)f2bf(v.x - bf2f((unsigned short)h.x));
            lo.y = (short)f2bf(v.y - bf2f((unsigned short)h.y));
            lo.z = (short)f2bf(v.z - bf2f((unsigned short)h.z));
            lo.w = (short)f2bf(v.w - bf2f((unsigned short)h.w));
            *(short4v*)&psH[row][j * 4] = h;
            *(short4v*)&psL[row][j * 4] = lo;
        }
        asm volatile("s_waitcnt lgkmcnt(0)" ::: "memory");  // own ds_writes done
        __builtin_amdgcn_s_barrier();                        // staging visible
        asm volatile("" ::: "memory");
        if (kc + 1 < KCN) {  // prefetch kc+1: in flight through MFMA + barriers
            int k0n = (kc + 1) * SKC;
#pragma unroll
            for (int ps = 0; ps < 4; ++ps)
                fv[ps] = *(const float4*)&fb[(size_t)(row + 32 * ps) * DD + k0n + j * 4];
            pv = *(const float4*)&pb[(size_t)row * DD + k0n + j * 4];
        }
        short8v ah = *(const short8v*)&psH[wp * 16 + (l & 15)][(l >> 4) * 8];
        short8v al = *(const short8v*)&psL[wp * 16 + (l & 15)][(l >> 4) * 8];
#pragma unroll
        for (int nf = 0; nf < 4; ++nf) {
            int nr = wn * 64 + nf * 16 + (l & 15);
            short8v bh = *(const short8v*)&fsH[nr][(l >> 4) * 8];
            short8v bl = *(const short8v*)&fsL[nr][(l >> 4) * 8];
            acc[nf] = __builtin_amdgcn_mfma_f32_16x16x32_bf16(ah, bh, acc[nf], 0, 0, 0);
            acc[nf] = __builtin_amdgcn_mfma_f32_16x16x32_bf16(ah, bl, acc[nf], 0, 0, 0);
            acc[nf] = __builtin_amdgcn_mfma_f32_16x16x32_bf16(al, bh, acc[nf], 0, 0, 0);
            acc[nf] = __builtin_amdgcn_mfma_f32_16x16x32_bf16(al, bl, acc[nf], 0, 0, 0);
        }
    }
    // norm reductions over 8-lane j-groups
#pragma unroll
    for (int ps = 0; ps < 4; ++ps) {
        float s = nacc[ps];
        s += __shfl_xor(s, 1, 64);
        s += __shfl_xor(s, 2, 64);
        s += __shfl_xor(s, 4, 64);
        if (j == 0) nfl[row + 32 * ps] = sqrtf(s);
    }
    {
        float s = pacc;
        s += __shfl_xor(s, 1, 64);
        s += __shfl_xor(s, 2, 64);
        s += __shfl_xor(s, 4, 64);
        if (j == 0) pnl[row] = sqrtf(s);
    }
    __syncthreads();
#pragma unroll
    for (int nf = 0; nf < 4; ++nf) {
        int nr = wn * 64 + nf * 16 + (l & 15);
        float fn = nfl[nr];
#pragma unroll
        for (int r = 0; r < 4; ++r) {
            int p = wp * 16 + (l >> 4) * 4 + r;
            float dnm = fmaxf(pnl[p] * fn, 1e-8f);
            out[(size_t)(b * PP + p) * NN + n0 + nr] = acc[nf][r] / dnm;
        }
    }
}

// ---- row stats: one WAVE per (b,p) row, grid BB*PP, 64 threads -----------
// Byte-identical per-wave instruction sequence to the fused version's
// phase 1 (same 16x float4 loop, same wsum/wmax, same density gather)
// -> bit-identical tt/xmax/Zr. Widens 32 blocks -> 1024 blocks.
__global__ __launch_bounds__(64) void kstats(const float* __restrict__ sim,
                                             const int* __restrict__ sortn,
                                             const int* __restrict__ cnt,
                                             const int* __restrict__ offs,
                                             float* __restrict__ tt,
                                             float* __restrict__ xmax,
                                             float* __restrict__ Zr,
                                             int hasPrev) {
    int bp = blockIdx.x;
    int b = bp >> 5, p = bp & 31;
    int lane = threadIdx.x;
    const float* sb = sim + (size_t)(b * PP) * NN;
    const float4* r4 = (const float4*)(sb + (size_t)p * NN);
    float mx = -3.4e38f;
    for (int q = 0; q < 16; ++q) {
        float4 x = r4[lane + 64 * q];
        mx = fmaxf(mx, fmaxf(fmaxf(x.x, x.y), fmaxf(x.z, x.w)));
    }
    float bm = wmax(mx);
    bm = __shfl(bm, 0, 64);
    float ttv;
    if (hasPrev) {
        int c = cnt[bp];
        const int* lp = sortn + (size_t)b * NN + offs[bp];
        float s = 0.f;
        for (int jj = lane; jj < c; jj += 64) s += sb[(size_t)p * NN + (lp[jj] & 0xFFF)];
        float sm = wsum(s);
        sm = __shfl(sm, 0, 64);
        float density = (c >= 1) ? (1.f - sm / (float)c) : 1.f;
        ttv = 0.1f * fmaxf(density, 1e-10f);
    } else {
        ttv = 0.01f;  // TEMP * TAU0
    }
    float xm = bm / ttv;
    float z = 0.f;
    for (int q = 0; q < 16; ++q) {
        float4 x = r4[lane + 64 * q];
        z += expf(x.x / ttv - xm) + expf(x.y / ttv - xm) +
             expf(x.z / ttv - xm) + expf(x.w / ttv - xm);
    }
    float zz = wsum(z);
    if (lane == 0) {
        tt[bp] = ttv;
        xmax[bp] = xm;
        Zr[bp] = zz;
    }
}

// ---- fused assign: argmax + counting sort (stats precomputed) ------------
// one block per b, 1024 threads = 16 waves. EXACT round-9 weight formula —
// the per-(n,p) comparison expression expf(s/tt-xm)/Z must not be reordered
// (round-10 log-space reformulation flipped near-tie argmaxes and failed).
__global__ __launch_bounds__(1024) void kassign(const float* __restrict__ sim,
                                                const float* __restrict__ tt,
                                                const float* __restrict__ xmax,
                                                const float* __restrict__ Zr,
                                                int* __restrict__ sortn,
                                                float* __restrict__ sortw,
                                                int* __restrict__ cnt,
                                                int* __restrict__ offs) {
    __shared__ float swv[NN];            // 16 KB weights
    __shared__ unsigned char sidx[NN];   // 4 KB argmax idx
    __shared__ int cntc[64][PP];         // 8 KB per-chunk per-p counts -> bases
    __shared__ float ttl[PP], xml[PP], zrl[PP];
    __shared__ int offp[PP], totl[PP];
    int b = blockIdx.x;
    int tid = threadIdx.x;
    int w = tid >> 6, lane = tid & 63;
    const float* sb = sim + (size_t)(b * PP) * NN;

    if (tid < PP) {
        ttl[tid] = tt[b * PP + tid];
        xml[tid] = xmax[b * PP + tid];
        zrl[tid] = Zr[b * PP + tid];
    }
    __syncthreads();

    // phase 2: per-n argmax + per-chunk counts (exact round-9 arithmetic)
    for (int ci = 0; ci < 4; ++ci) {
        int c = w + 16 * ci;
        int n = c * 64 + lane;
        float best = -1.f;
        int bi = 0;
#pragma unroll
        for (int p = 0; p < PP; ++p) {
            float s = sb[(size_t)p * NN + n];
            float wgt = expf(s / ttl[p] - xml[p]) / zrl[p];
            if (wgt > best) { best = wgt; bi = p; }
        }
        sidx[n] = (unsigned char)bi;
        swv[n] = best;
#pragma unroll
        for (int p = 0; p < PP; ++p) {
            unsigned long long bal = __ballot(bi == p);
            if (lane == p) cntc[c][p] = __popcll(bal);
        }
    }
    __syncthreads();

    // phase 3: per-p prefix over chunks, then exclusive prefix over p
    if (tid < PP) {
        int run = 0;
        for (int c = 0; c < 64; ++c) {
            int t_ = cntc[c][tid];
            cntc[c][tid] = run;
            run += t_;
        }
        totl[tid] = run;
        cnt[b * PP + tid] = run;
    }
    __syncthreads();
    if (tid == 0) {
        int s = 0;
        for (int p = 0; p < PP; ++p) {
            offp[p] = s;
            offs[b * PP + p] = s;
            s += totl[p];
        }
    }
    __syncthreads();

    // phase 4: stable scatter (ascending n within bucket)
    for (int ci = 0; ci < 4; ++ci) {
        int c = w + 16 * ci;
        int n = c * 64 + lane;
        int bi = sidx[n];
        float wgt = swv[n];
        unsigned long long below = (1ull << lane) - 1ull;
#pragma unroll
        for (int p = 0; p < PP; ++p) {
            unsigned long long bal = __ballot(bi == p);
            if (bi == p) {
                int rank = __popcll(bal & below);
                int pos = offp[p] + cntc[c][p] + rank;
                sortn[(size_t)b * NN + pos] = (p << 12) | n;
                sortw[(size_t)b * NN + pos] = wgt;
            }
        }
    }
}

// ---- update: 64-row window, float4 gather with 4-deep register prefetch --
#define UPD_STEP(FREG, JIDX, NXT)                                          \
    {                                                                      \
        int e = sn[JIDX];                                                  \
        int p = e >> 12;                                                   \
        float wv = sw[JIDX];                                               \
        float4 f = FREG;                                                   \
        if ((NXT) < WROWS) FREG = fb[(size_t)(sn[NXT] & 0xFFF) * 192 + t]; \
        if (p != curp) {                                                   \
            float4 o = {ax, ay, az, aw};                                   \
            pw[(size_t)curp * 192 + t] = o;                                \
            ax = ay = az = aw = 0.f;                                       \
            curp = p;                                                      \
        }                                                                  \
        ax = fmaf(wv, f.x, ax);                                            \
        ay = fmaf(wv, f.y, ay);                                            \
        az = fmaf(wv, f.z, az);                                            \
        aw = fmaf(wv, f.w, aw);                                            \
    }

__global__ __launch_bounds__(192) void kupdate(const float* __restrict__ feats,
                                               const int* __restrict__ sortn,
                                               const float* __restrict__ sortw,
                                               float* __restrict__ part) {
    __shared__ int sn[WROWS];
    __shared__ float sw[WROWS];
    int win = blockIdx.x & (NWIN - 1);
    int b = blockIdx.x >> 6;
    int t = threadIdx.x;
    if (t < WROWS) {
        sn[t] = sortn[b * NN + win * WROWS + t];
        sw[t] = sortw[b * NN + win * WROWS + t];
    }
    __syncthreads();
    const float4* fb = (const float4*)(feats + (size_t)b * NN * DD);
    float4* pw = (float4*)(part + (size_t)(b * NWIN + win) * PP * DD);
    float ax = 0.f, ay = 0.f, az = 0.f, aw = 0.f;
    int curp = sn[0] >> 12;
    float4 fp0 = fb[(size_t)(sn[0] & 0xFFF) * 192 + t];
    float4 fp1 = fb[(size_t)(sn[1] & 0xFFF) * 192 + t];
    float4 fp2 = fb[(size_t)(sn[2] & 0xFFF) * 192 + t];
    float4 fp3 = fb[(size_t)(sn[3] & 0xFFF) * 192 + t];
    for (int jj = 0; jj < WROWS; jj += 4) {
        UPD_STEP(fp0, jj + 0, jj + 4);
        UPD_STEP(fp1, jj + 1, jj + 5);
        UPD_STEP(fp2, jj + 2, jj + 6);
        UPD_STEP(fp3, jj + 3, jj + 7);
    }
    float4 o = {ax, ay, az, aw};
    pw[(size_t)curp * 192 + t] = o;
}

// ---- reduce window partials -> prototypes (+ final out) ------------------
__global__ __launch_bounds__(192) void kreduce(const float* __restrict__ part,
                                               const int* __restrict__ offs,
                                               const int* __restrict__ cnt,
                                               float* __restrict__ prot,
                                               float* __restrict__ outp) {
    int bp = blockIdx.x;
    int b = bp >> 5, p = bp & 31;
    int t = threadIdx.x;
    float4 s = {0.f, 0.f, 0.f, 0.f};
    int c = cnt[bp];
    if (c > 0) {
        int j0 = offs[bp];
        int w0 = j0 >> 6, w1 = (j0 + c - 1) >> 6;
        const float4* pr = (const float4*)(part);
        for (int w = w0; w <= w1; ++w) {
            float4 v = pr[(size_t)((b * NWIN + w) * PP + p) * 192 + t];
            s.x += v.x; s.y += v.y; s.z += v.z; s.w += v.w;
        }
    }
    ((float4*)(prot + (size_t)bp * DD))[t] = s;
    if (outp) ((float4*)(outp + (size_t)bp * DD))[t] = s;
}

extern "C" void kernel_launch(void* const* d_in, const int* in_sizes, int n_in,
                              void* d_out, int out_size, void* d_ws, size_t ws_size,
                              hipStream_t stream) {
    const float* protIn = (const float*)d_in[0];
    const float* feats = (const float*)d_in[1];
    const float* forg = (const float*)d_in[2];
    float* out = (float*)d_out;

    char* w = (char*)d_ws;
    auto alloc = [&](size_t bytes) {
        char* p = w;
        w += (bytes + 255) & ~(size_t)255;
        return p;
    };
    float* sim = (float*)alloc((size_t)BB * PP * NN * 4);
    float* prot = (float*)alloc((size_t)BB * PP * DD * 4);
    float* part = (float*)alloc((size_t)BB * NWIN * PP * DD * 4);
    float* ttb = (float*)alloc(BB * PP * 4);
    float* xmaxb = (float*)alloc(BB * PP * 4);
    float* Zrb = (float*)alloc(BB * PP * 4);
    int* sortn = (int*)alloc((size_t)BB * NN * 4);
    float* sortw = (float*)alloc((size_t)BB * NN * 4);
    int* cnt = (int*)alloc(BB * PP * 4);
    int* offs = (int*)alloc(BB * PP * 4);

    for (int t = 0; t < 5; ++t) {
        ksim<<<BB * SNT, 256, 0, stream>>>(t == 0 ? protIn : prot, feats,
                                           (size_t)NN * DD, sim);
        kstats<<<BB * PP, 64, 0, stream>>>(sim, sortn, cnt, offs, ttb, xmaxb, Zrb,
                                           t > 0 ? 1 : 0);
        kassign<<<BB, 1024, 0, stream>>>(sim, ttb, xmaxb, Zrb, sortn, sortw, cnt,
                                         offs);
        kupdate<<<BB * NWIN, 192, 0, stream>>>(feats, sortn, sortw, part);
        kreduce<<<BB * PP, 192, 0, stream>>>(part, offs, cnt, prot,
                                             (t == 4) ? out : nullptr);
    }
    // final similarity against feats_org (broadcast fsb=0) -> second output
    ksim<<<BB * SNT, 256, 0, stream>>>(prot, forg, (size_t)0,
                                       out + (size_t)BB * PP * DD);
}

// Round 16
// 1089.230 us; speedup vs baseline: 1.3004x; 1.1645x over previous
//
#include <hip/hip_runtime.h>
#include <math.h>

#define BB 32
#define PP 32
#define NN 4096
#define DD 768
#define MM 4096
#define WROWS 64           // rows per update window
#define NWIN (NN / WROWS)  // 64 windows per b
#define SIMB 128           // n per ksim block
#define SNT (NN / SIMB)    // 32 n-tiles
#define SKC 32             // k chunk in ksim
#define KCN (DD / SKC)     // 24 k-chunks
#define FPAD 40            // shorts per LDS row (32 + 8 pad)

typedef __attribute__((ext_vector_type(8))) short short8v;
typedef __attribute__((ext_vector_type(4))) short short4v;
typedef __attribute__((ext_vector_type(4))) float float4v;

__device__ __forceinline__ float wsum(float v) {
    for (int o = 32; o > 0; o >>= 1) v += __shfl_down(v, o, 64);
    return v;
}
__device__ __forceinline__ float wmax(float v) {
    for (int o = 32; o > 0; o >>= 1) v = fmaxf(v, __shfl_down(v, o, 64));
    return v;
}
__device__ __forceinline__ unsigned short f2bf(float x) {  // RNE float->bf16
    unsigned u = __float_as_uint(x);
    return (unsigned short)((u + 0x7FFFu + ((u >> 16) & 1u)) >> 16);
}
__device__ __forceinline__ float bf2f(unsigned short h) {
    return __uint_as_float((unsigned)h << 16);
}

// ---- cosine-sim GEMM via bf16 MFMA, exact 4-term hi/lo split -------------
// grid: BB*SNT blocks, 256 threads (4 waves); wave tile 16p x 64n.
// Round-9/12 structure (proven): raw-barrier pipeline, prefetch kc+1 in
// flight across MFMA + barriers. Do not restructure — reg-direct (r13),
// conversion-hoist (r14), tile changes (r4, r12) were all neutral/worse.
__global__ __launch_bounds__(256) void ksim(
    const float* __restrict__ prot, const float* __restrict__ feats,
    size_t fsb, float* __restrict__ out) {
    __shared__ short fsH[SIMB][FPAD];
    __shared__ short fsL[SIMB][FPAD];
    __shared__ short psH[PP][FPAD];
    __shared__ short psL[PP][FPAD];
    __shared__ float nfl[SIMB];
    __shared__ float pnl[PP];
    int bid = blockIdx.x;
    int b = bid >> 5, nt = bid & 31;
    int n0 = nt * SIMB;
    int tid = threadIdx.x;
    int row = tid >> 3, j = tid & 7;  // 8 threads per row (32 rows/pass)
    int l = tid & 63, w = tid >> 6;
    int wp = w & 1, wn = w >> 1;      // wave tile: 16p x 64n
    const float* fb = feats + (size_t)b * fsb + (size_t)n0 * DD;
    const float* pb = prot + (size_t)b * (PP * DD);
    float4v acc[4] = {};
    float nacc[4] = {};
    float pacc = 0.f;
    float4 fv[4], pv;
#pragma unroll
    for (int ps = 0; ps < 4; ++ps)
        fv[ps] = *(const float4*)&fb[(size_t)(row + 32 * ps) * DD + j * 4];
    pv = *(const float4*)&pb[(size_t)row * DD + j * 4];
    for (int kc = 0; kc < KCN; ++kc) {
        __builtin_amdgcn_s_barrier();  // all waves done reading LDS
        asm volatile("" ::: "memory");
#pragma unroll
        for (int ps = 0; ps < 4; ++ps) {
            float4 v = fv[ps];
            nacc[ps] += v.x * v.x + v.y * v.y + v.z * v.z + v.w * v.w;
            short4v h, lo;
            h.x = (short)f2bf(v.x); h.y = (short)f2bf(v.y);
            h.z = (short)f2bf(v.z); h.w = (short)f2bf(v.w);
            lo.x = (short)f2bf(v.x - bf2f((unsigned short)h.x));
            lo.y = (short)f2bf(v.y - bf2f((unsigned short)h.y));
            lo.z = (short)f2bf(v.z - bf2f((unsigned short)h.z));
            lo.w = (short)f2bf(v.w - bf2f((unsigned short)h.w));
            *(short4v*)&fsH[row + 32 * ps][j * 4] = h;
            *(short4v*)&fsL[row + 32 * ps][j * 4] = lo;
        }
        {
            float4 v = pv;
            pacc += v.x * v.x + v.y * v.y + v.z * v.z + v.w * v.w;
            short4v h, lo;
            h.x = (short)f2bf(v.x); h.y = (short)f2bf(v.y);
            h.z = (short)f2bf(v.z); h.w = (short)f2bf(v.w);
            lo.x = (short)f2bf(v.x - bf2f((unsigned short)h.x));
            lo.y = (short)f2bf(v.y - bf2f((unsigned short)h.y));
            lo.z = (short)f2bf(v.z - bf2f((unsigned short)h.z));
            lo.w = (short)f2bf(v.w - bf2f((unsigned short)h.w));
            *(short4v*)&psH[row][j * 4] = h;
            *(short4v*)&psL[row][j * 4] = lo;
        }
        asm volatile("s_waitcnt lgkmcnt(0)" ::: "memory");  // own ds_writes done
        __builtin_amdgcn_s_barrier();                        // staging visible
        asm volatile("" ::: "memory");
        if (kc + 1 < KCN) {  // prefetch kc+1: in flight through MFMA + barriers
            int k0n = (kc + 1) * SKC;
#pragma unroll
            for (int ps = 0; ps < 4; ++ps)
                fv[ps] = *(const float4*)&fb[(size_t)(row + 32 * ps) * DD + k0n + j * 4];
            pv = *(const float4*)&pb[(size_t)row * DD + k0n + j * 4];
        }
        short8v ah = *(const short8v*)&psH[wp * 16 + (l & 15)][(l >> 4) * 8];
        short8v al = *(const short8v*)&psL[wp * 16 + (l & 15)][(l >> 4) * 8];
#pragma unroll
        for (int nf = 0; nf < 4; ++nf) {
            int nr = wn * 64 + nf * 16 + (l & 15);
            short8v bh = *(const short8v*)&fsH[nr][(l >> 4) * 8];
            short8v bl = *(const short8v*)&fsL[nr][(l >> 4) * 8];
            acc[nf] = __builtin_amdgcn_mfma_f32_16x16x32_bf16(ah, bh, acc[nf], 0, 0, 0);
            acc[nf] = __builtin_amdgcn_mfma_f32_16x16x32_bf16(ah, bl, acc[nf], 0, 0, 0);
            acc[nf] = __builtin_amdgcn_mfma_f32_16x16x32_bf16(al, bh, acc[nf], 0, 0, 0);
            acc[nf] = __builtin_amdgcn_mfma_f32_16x16x32_bf16(al, bl, acc[nf], 0, 0, 0);
        }
    }
    // norm reductions over 8-lane j-groups
#pragma unroll
    for (int ps = 0; ps < 4; ++ps) {
        float s = nacc[ps];
        s += __shfl_xor(s, 1, 64);
        s += __shfl_xor(s, 2, 64);
        s += __shfl_xor(s, 4, 64);
        if (j == 0) nfl[row + 32 * ps] = sqrtf(s);
    }
    {
        float s = pacc;
        s += __shfl_xor(s, 1, 64);
        s += __shfl_xor(s, 2, 64);
        s += __shfl_xor(s, 4, 64);
        if (j == 0) pnl[row] = sqrtf(s);
    }
    __syncthreads();
#pragma unroll
    for (int nf = 0; nf < 4; ++nf) {
        int nr = wn * 64 + nf * 16 + (l & 15);
        float fn = nfl[nr];
#pragma unroll
        for (int r = 0; r < 4; ++r) {
            int p = wp * 16 + (l >> 4) * 4 + r;
            float dnm = fmaxf(pnl[p] * fn, 1e-8f);
            out[(size_t)(b * PP + p) * NN + n0 + nr] = acc[nf][r] / dnm;
        }
    }
}

// ---- row stats: one WAVE per (b,p) row, grid BB*PP, 64 threads -----------
__global__ __launch_bounds__(64) void kstats(const float* __restrict__ sim,
                                             const int* __restrict__ sortn,
                                             const int* __restrict__ cnt,
                                             const int* __restrict__ offs,
                                             float* __restrict__ tt,
                                             float* __restrict__ xmax,
                                             float* __restrict__ Zr,
                                             int hasPrev) {
    int bp = blockIdx.x;
    int b = bp >> 5, p = bp & 31;
    int lane = threadIdx.x;
    const float* sb = sim + (size_t)(b * PP) * NN;
    const float4* r4 = (const float4*)(sb + (size_t)p * NN);
    float mx = -3.4e38f;
    for (int q = 0; q < 16; ++q) {
        float4 x = r4[lane + 64 * q];
        mx = fmaxf(mx, fmaxf(fmaxf(x.x, x.y), fmaxf(x.z, x.w)));
    }
    float bm = wmax(mx);
    bm = __shfl(bm, 0, 64);
    float ttv;
    if (hasPrev) {
        int c = cnt[bp];
        const int* lp = sortn + (size_t)b * NN + offs[bp];
        float s = 0.f;
        for (int jj = lane; jj < c; jj += 64) s += sb[(size_t)p * NN + (lp[jj] & 0xFFF)];
        float sm = wsum(s);
        sm = __shfl(sm, 0, 64);
        float density = (c >= 1) ? (1.f - sm / (float)c) : 1.f;
        ttv = 0.1f * fmaxf(density, 1e-10f);
    } else {
        ttv = 0.01f;  // TEMP * TAU0
    }
    float xm = bm / ttv;
    float z = 0.f;
    for (int q = 0; q < 16; ++q) {
        float4 x = r4[lane + 64 * q];
        z += expf(x.x / ttv - xm) + expf(x.y / ttv - xm) +
             expf(x.z / ttv - xm) + expf(x.w / ttv - xm);
    }
    float zz = wsum(z);
    if (lane == 0) {
        tt[bp] = ttv;
        xmax[bp] = xm;
        Zr[bp] = zz;
    }
}

// ---- wide argmax: grid BB*16 blocks, 256 thr; each wave owns one 64-chunk.
// EXACT round-9 weight formula — the per-(n,p) comparison expression
// expf(s/tt-xm)/Z must not be reordered (round-10 lesson). Emits sidx/swv
// plus per-chunk per-p counts (ballot), all to global.
__global__ __launch_bounds__(256) void karg(const float* __restrict__ sim,
                                            const float* __restrict__ tt,
                                            const float* __restrict__ xmax,
                                            const float* __restrict__ Zr,
                                            unsigned char* __restrict__ sidxg,
                                            float* __restrict__ swvg,
                                            int* __restrict__ cntcg) {
    __shared__ float ttl[PP], xml[PP], zrl[PP];
    int bid = blockIdx.x;
    int b = bid >> 4, q = bid & 15;
    int tid = threadIdx.x;
    int wv = tid >> 6, lane = tid & 63;
    if (tid < PP) {
        ttl[tid] = tt[b * PP + tid];
        xml[tid] = xmax[b * PP + tid];
        zrl[tid] = Zr[b * PP + tid];
    }
    __syncthreads();
    const float* sb = sim + (size_t)(b * PP) * NN;
    int c = q * 4 + wv;
    int n = c * 64 + lane;
    float best = -1.f;
    int bi = 0;
#pragma unroll
    for (int p = 0; p < PP; ++p) {
        float s = sb[(size_t)p * NN + n];
        float wgt = expf(s / ttl[p] - xml[p]) / zrl[p];
        if (wgt > best) { best = wgt; bi = p; }
    }
    sidxg[(size_t)b * NN + n] = (unsigned char)bi;
    swvg[(size_t)b * NN + n] = best;
#pragma unroll
    for (int p = 0; p < PP; ++p) {
        unsigned long long bal = __ballot(bi == p);
        if (lane == p) cntcg[((size_t)b * 64 + c) * PP + p] = __popcll(bal);
    }
}

// ---- assign: prefix + stable scatter only (argmax precomputed) -----------
// one block per b, 1024 threads = 16 waves. Prefix & scatter orders are
// instruction-identical to round 15 -> bit-identical sortn/sortw/cnt/offs.
__global__ __launch_bounds__(1024) void kassign(const unsigned char* __restrict__ sidxg,
                                                const float* __restrict__ swvg,
                                                const int* __restrict__ cntcg,
                                                int* __restrict__ sortn,
                                                float* __restrict__ sortw,
                                                int* __restrict__ cnt,
                                                int* __restrict__ offs) {
    __shared__ int cntc[64][PP];         // 8 KB per-chunk per-p counts -> bases
    __shared__ int offp[PP], totl[PP];
    int b = blockIdx.x;
    int tid = threadIdx.x;
    int w = tid >> 6, lane = tid & 63;
    // load per-chunk counts (2048 ints, 2 per thread)
    cntc[tid >> 5][tid & 31] = cntcg[(size_t)b * 64 * PP + tid];
    cntc[32 + (tid >> 5)][tid & 31] = cntcg[(size_t)b * 64 * PP + 1024 + tid];
    __syncthreads();

    // phase 3: per-p prefix over chunks, then exclusive prefix over p
    if (tid < PP) {
        int run = 0;
        for (int c = 0; c < 64; ++c) {
            int t_ = cntc[c][tid];
            cntc[c][tid] = run;
            run += t_;
        }
        totl[tid] = run;
        cnt[b * PP + tid] = run;
    }
    __syncthreads();
    if (tid == 0) {
        int s = 0;
        for (int p = 0; p < PP; ++p) {
            offp[p] = s;
            offs[b * PP + p] = s;
            s += totl[p];
        }
    }
    __syncthreads();

    // phase 4: stable scatter (ascending n within bucket)
    for (int ci = 0; ci < 4; ++ci) {
        int c = w + 16 * ci;
        int n = c * 64 + lane;
        int bi = sidxg[(size_t)b * NN + n];
        float wgt = swvg[(size_t)b * NN + n];
        unsigned long long below = (1ull << lane) - 1ull;
#pragma unroll
        for (int p = 0; p < PP; ++p) {
            unsigned long long bal = __ballot(bi == p);
            if (bi == p) {
                int rank = __popcll(bal & below);
                int pos = offp[p] + cntc[c][p] + rank;
                sortn[(size_t)b * NN + pos] = (p << 12) | n;
                sortw[(size_t)b * NN + pos] = wgt;
            }
        }
    }
}

// ---- update: 64-row window, float4 gather with 4-deep register prefetch --
#define UPD_STEP(FREG, JIDX, NXT)                                          \
    {                                                                      \
        int e = sn[JIDX];                                                  \
        int p = e >> 12;                                                   \
        float wv = sw[JIDX];                                               \
        float4 f = FREG;                                                   \
        if ((NXT) < WROWS) FREG = fb[(size_t)(sn[NXT] & 0xFFF) * 192 + t]; \
        if (p != curp) {                                                   \
            float4 o = {ax, ay, az, aw};                                   \
            pw[(size_t)curp * 192 + t] = o;                                \
            ax = ay = az = aw = 0.f;                                       \
            curp = p;                                                      \
        }                                                                  \
        ax = fmaf(wv, f.x, ax);                                            \
        ay = fmaf(wv, f.y, ay);                                            \
        az = fmaf(wv, f.z, az);                                            \
        aw = fmaf(wv, f.w, aw);                                            \
    }

__global__ __launch_bounds__(192) void kupdate(const float* __restrict__ feats,
                                               const int* __restrict__ sortn,
                                               const float* __restrict__ sortw,
                                               float* __restrict__ part) {
    __shared__ int sn[WROWS];
    __shared__ float sw[WROWS];
    int win = blockIdx.x & (NWIN - 1);
    int b = blockIdx.x >> 6;
    int t = threadIdx.x;
    if (t < WROWS) {
        sn[t] = sortn[b * NN + win * WROWS + t];
        sw[t] = sortw[b * NN + win * WROWS + t];
    }
    __syncthreads();
    const float4* fb = (const float4*)(feats + (size_t)b * NN * DD);
    float4* pw = (float4*)(part + (size_t)(b * NWIN + win) * PP * DD);
    float ax = 0.f, ay = 0.f, az = 0.f, aw = 0.f;
    int curp = sn[0] >> 12;
    float4 fp0 = fb[(size_t)(sn[0] & 0xFFF) * 192 + t];
    float4 fp1 = fb[(size_t)(sn[1] & 0xFFF) * 192 + t];
    float4 fp2 = fb[(size_t)(sn[2] & 0xFFF) * 192 + t];
    float4 fp3 = fb[(size_t)(sn[3] & 0xFFF) * 192 + t];
    for (int jj = 0; jj < WROWS; jj += 4) {
        UPD_STEP(fp0, jj + 0, jj + 4);
        UPD_STEP(fp1, jj + 1, jj + 5);
        UPD_STEP(fp2, jj + 2, jj + 6);
        UPD_STEP(fp3, jj + 3, jj + 7);
    }
    float4 o = {ax, ay, az, aw};
    pw[(size_t)curp * 192 + t] = o;
}

// ---- reduce window partials -> prototypes (+ final out) ------------------
__global__ __launch_bounds__(192) void kreduce(const float* __restrict__ part,
                                               const int* __restrict__ offs,
                                               const int* __restrict__ cnt,
                                               float* __restrict__ prot,
                                               float* __restrict__ outp) {
    int bp = blockIdx.x;
    int b = bp >> 5, p = bp & 31;
    int t = threadIdx.x;
    float4 s = {0.f, 0.f, 0.f, 0.f};
    int c = cnt[bp];
    if (c > 0) {
        int j0 = offs[bp];
        int w0 = j0 >> 6, w1 = (j0 + c - 1) >> 6;
        const float4* pr = (const float4*)(part);
        for (int w = w0; w <= w1; ++w) {
            float4 v = pr[(size_t)((b * NWIN + w) * PP + p) * 192 + t];
            s.x += v.x; s.y += v.y; s.z += v.z; s.w += v.w;
        }
    }
    ((float4*)(prot + (size_t)bp * DD))[t] = s;
    if (outp) ((float4*)(outp + (size_t)bp * DD))[t] = s;
}

extern "C" void kernel_launch(void* const* d_in, const int* in_sizes, int n_in,
                              void* d_out, int out_size, void* d_ws, size_t ws_size,
                              hipStream_t stream) {
    const float* protIn = (const float*)d_in[0];
    const float* feats = (const float*)d_in[1];
    const float* forg = (const float*)d_in[2];
    float* out = (float*)d_out;

    char* w = (char*)d_ws;
    auto alloc = [&](size_t bytes) {
        char* p = w;
        w += (bytes + 255) & ~(size_t)255;
        return p;
    };
    float* sim = (float*)alloc((size_t)BB * PP * NN * 4);
    float* prot = (float*)alloc((size_t)BB * PP * DD * 4);
    float* part = (float*)alloc((size_t)BB * NWIN * PP * DD * 4);
    float* ttb = (float*)alloc(BB * PP * 4);
    float* xmaxb = (float*)alloc(BB * PP * 4);
    float* Zrb = (float*)alloc(BB * PP * 4);
    unsigned char* sidxg = (unsigned char*)alloc((size_t)BB * NN);
    float* swvg = (float*)alloc((size_t)BB * NN * 4);
    int* cntcg = (int*)alloc((size_t)BB * 64 * PP * 4);
    int* sortn = (int*)alloc((size_t)BB * NN * 4);
    float* sortw = (float*)alloc((size_t)BB * NN * 4);
    int* cnt = (int*)alloc(BB * PP * 4);
    int* offs = (int*)alloc(BB * PP * 4);

    for (int t = 0; t < 5; ++t) {
        ksim<<<BB * SNT, 256, 0, stream>>>(t == 0 ? protIn : prot, feats,
                                           (size_t)NN * DD, sim);
        kstats<<<BB * PP, 64, 0, stream>>>(sim, sortn, cnt, offs, ttb, xmaxb, Zrb,
                                           t > 0 ? 1 : 0);
        karg<<<BB * 16, 256, 0, stream>>>(sim, ttb, xmaxb, Zrb, sidxg, swvg, cntcg);
        kassign<<<BB, 1024, 0, stream>>>(sidxg, swvg, cntcg, sortn, sortw, cnt, offs);
        kupdate<<<BB * NWIN, 192, 0, stream>>>(feats, sortn, sortw, part);
        kreduce<<<BB * PP, 192, 0, stream>>>(part, offs, cnt, prot,
                                             (t == 4) ? out : nullptr);
    }
    // final similarity against feats_org (broadcast fsb=0) -> second output
    ksim<<<BB * SNT, 256, 0, stream>>>(prot, forg, (size_t)0,
                                       out + (size_t)BB * PP * DD);
}

// Round 17
// 1073.314 us; speedup vs baseline: 1.3197x; 1.0148x over previous
//
#include <hip/hip_runtime.h>
#include <math.h>

#define BB 32
#define PP 32
#define NN 4096
#define DD 768
#define MM 4096
#define WROWS 64           // rows per update window
#define NWIN (NN / WROWS)  // 64 windows per b
#define SIMB 128           // n per ksim block
#define SNT (NN / SIMB)    // 32 n-tiles
#define SKC 32             // k chunk in ksim
#define KCN (DD / SKC)     // 24 k-chunks
#define FPAD 40            // shorts per LDS row (32 + 8 pad)

typedef __attribute__((ext_vector_type(8))) short short8v;
typedef __attribute__((ext_vector_type(4))) short short4v;
typedef __attribute__((ext_vector_type(4))) float float4v;

__device__ __forceinline__ float wsum(float v) {
    for (int o = 32; o > 0; o >>= 1) v += __shfl_down(v, o, 64);
    return v;
}
__device__ __forceinline__ float wmax(float v) {
    for (int o = 32; o > 0; o >>= 1) v = fmaxf(v, __shfl_down(v, o, 64));
    return v;
}
__device__ __forceinline__ unsigned short f2bf(float x) {  // RNE float->bf16
    unsigned u = __float_as_uint(x);
    return (unsigned short)((u + 0x7FFFu + ((u >> 16) & 1u)) >> 16);
}
__device__ __forceinline__ float bf2f(unsigned short h) {
    return __uint_as_float((unsigned)h << 16);
}

// ---- cosine-sim GEMM via bf16 MFMA, exact 4-term hi/lo split -------------
// grid: BB*SNT blocks, 256 threads (4 waves); wave tile 16p x 64n.
// Round-9/12 structure (proven): raw-barrier pipeline, prefetch kc+1 in
// flight across MFMA + barriers. Do not restructure — reg-direct (r13),
// conversion-hoist (r14), tile changes (r4, r12) were all neutral/worse.
__global__ __launch_bounds__(256) void ksim(
    const float* __restrict__ prot, const float* __restrict__ feats,
    size_t fsb, float* __restrict__ out) {
    __shared__ short fsH[SIMB][FPAD];
    __shared__ short fsL[SIMB][FPAD];
    __shared__ short psH[PP][FPAD];
    __shared__ short psL[PP][FPAD];
    __shared__ float nfl[SIMB];
    __shared__ float pnl[PP];
    int bid = blockIdx.x;
    int b = bid >> 5, nt = bid & 31;
    int n0 = nt * SIMB;
    int tid = threadIdx.x;
    int row = tid >> 3, j = tid & 7;  // 8 threads per row (32 rows/pass)
    int l = tid & 63, w = tid >> 6;
    int wp = w & 1, wn = w >> 1;      // wave tile: 16p x 64n
    const float* fb = feats + (size_t)b * fsb + (size_t)n0 * DD;
    const float* pb = prot + (size_t)b * (PP * DD);
    float4v acc[4] = {};
    float nacc[4] = {};
    float pacc = 0.f;
    float4 fv[4], pv;
#pragma unroll
    for (int ps = 0; ps < 4; ++ps)
        fv[ps] = *(const float4*)&fb[(size_t)(row + 32 * ps) * DD + j * 4];
    pv = *(const float4*)&pb[(size_t)row * DD + j * 4];
    for (int kc = 0; kc < KCN; ++kc) {
        __builtin_amdgcn_s_barrier();  // all waves done reading LDS
        asm volatile("" ::: "memory");
#pragma unroll
        for (int ps = 0; ps < 4; ++ps) {
            float4 v = fv[ps];
            nacc[ps] += v.x * v.x + v.y * v.y + v.z * v.z + v.w * v.w;
            short4v h, lo;
            h.x = (short)f2bf(v.x); h.y = (short)f2bf(v.y);
            h.z = (short)f2bf(v.z); h.w = (short)f2bf(v.w);
            lo.x = (short)f2bf(v.x - bf2f((unsigned short)h.x));
            lo.y = (short)f2bf(v.y - bf2f((unsigned short)h.y));
            lo.z = (short)f2bf(v.z - bf2f((unsigned short)h.z));
            lo.w = (short)f2bf(v.w - bf2f((unsigned short)h.w));
            *(short4v*)&fsH[row + 32 * ps][j * 4] = h;
            *(short4v*)&fsL[row + 32 * ps][j * 4] = lo;
        }
        {
            float4 v = pv;
            pacc += v.x * v.x + v.y * v.y + v.z * v.z + v.w * v.w;
            short4v h, lo;
            h.x = (short)f2bf(v.x); h.y = (short)f2bf(v.y);
            h.z = (short)f2bf(v.z); h.w = (short)f2bf(v.w);
            lo.x = (short)f2bf(v.x - bf2f((unsigned short)h.x));
            lo.y = (short)f2bf(v.y - bf2f((unsigned short)h.y));
            lo.z = (short)f2bf(v.z - bf2f((unsigned short)h.z));
            lo.w = (short)f2bf(v.w - bf2f((unsigned short)h.w));
            *(short4v*)&psH[row][j * 4] = h;
            *(short4v*)&psL[row][j * 4] = lo;
        }
        asm volatile("s_waitcnt lgkmcnt(0)" ::: "memory");  // own ds_writes done
        __builtin_amdgcn_s_barrier();                        // staging visible
        asm volatile("" ::: "memory");
        if (kc + 1 < KCN) {  // prefetch kc+1: in flight through MFMA + barriers
            int k0n = (kc + 1) * SKC;
#pragma unroll
            for (int ps = 0; ps < 4; ++ps)
                fv[ps] = *(const float4*)&fb[(size_t)(row + 32 * ps) * DD + k0n + j * 4];
            pv = *(const float4*)&pb[(size_t)row * DD + k0n + j * 4];
        }
        short8v ah = *(const short8v*)&psH[wp * 16 + (l & 15)][(l >> 4) * 8];
        short8v al = *(const short8v*)&psL[wp * 16 + (l & 15)][(l >> 4) * 8];
#pragma unroll
        for (int nf = 0; nf < 4; ++nf) {
            int nr = wn * 64 + nf * 16 + (l & 15);
            short8v bh = *(const short8v*)&fsH[nr][(l >> 4) * 8];
            short8v bl = *(const short8v*)&fsL[nr][(l >> 4) * 8];
            acc[nf] = __builtin_amdgcn_mfma_f32_16x16x32_bf16(ah, bh, acc[nf], 0, 0, 0);
            acc[nf] = __builtin_amdgcn_mfma_f32_16x16x32_bf16(ah, bl, acc[nf], 0, 0, 0);
            acc[nf] = __builtin_amdgcn_mfma_f32_16x16x32_bf16(al, bh, acc[nf], 0, 0, 0);
            acc[nf] = __builtin_amdgcn_mfma_f32_16x16x32_bf16(al, bl, acc[nf], 0, 0, 0);
        }
    }
    // norm reductions over 8-lane j-groups
#pragma unroll
    for (int ps = 0; ps < 4; ++ps) {
        float s = nacc[ps];
        s += __shfl_xor(s, 1, 64);
        s += __shfl_xor(s, 2, 64);
        s += __shfl_xor(s, 4, 64);
        if (j == 0) nfl[row + 32 * ps] = sqrtf(s);
    }
    {
        float s = pacc;
        s += __shfl_xor(s, 1, 64);
        s += __shfl_xor(s, 2, 64);
        s += __shfl_xor(s, 4, 64);
        if (j == 0) pnl[row] = sqrtf(s);
    }
    __syncthreads();
#pragma unroll
    for (int nf = 0; nf < 4; ++nf) {
        int nr = wn * 64 + nf * 16 + (l & 15);
        float fn = nfl[nr];
#pragma unroll
        for (int r = 0; r < 4; ++r) {
            int p = wp * 16 + (l >> 4) * 4 + r;
            float dnm = fmaxf(pnl[p] * fn, 1e-8f);
            out[(size_t)(b * PP + p) * NN + n0 + nr] = acc[nf][r] / dnm;
        }
    }
}

// ---- row stats: one WAVE per (b,p) row, grid BB*PP, 64 threads -----------
__global__ __launch_bounds__(64) void kstats(const float* __restrict__ sim,
                                             const int* __restrict__ sortn,
                                             const int* __restrict__ cnt,
                                             const int* __restrict__ offs,
                                             float* __restrict__ tt,
                                             float* __restrict__ xmax,
                                             float* __restrict__ Zr,
                                             int hasPrev) {
    int bp = blockIdx.x;
    int b = bp >> 5, p = bp & 31;
    int lane = threadIdx.x;
    const float* sb = sim + (size_t)(b * PP) * NN;
    const float4* r4 = (const float4*)(sb + (size_t)p * NN);
    float mx = -3.4e38f;
    for (int q = 0; q < 16; ++q) {
        float4 x = r4[lane + 64 * q];
        mx = fmaxf(mx, fmaxf(fmaxf(x.x, x.y), fmaxf(x.z, x.w)));
    }
    float bm = wmax(mx);
    bm = __shfl(bm, 0, 64);
    float ttv;
    if (hasPrev) {
        int c = cnt[bp];
        const int* lp = sortn + (size_t)b * NN + offs[bp];
        float s = 0.f;
        for (int jj = lane; jj < c; jj += 64) s += sb[(size_t)p * NN + (lp[jj] & 0xFFF)];
        float sm = wsum(s);
        sm = __shfl(sm, 0, 64);
        float density = (c >= 1) ? (1.f - sm / (float)c) : 1.f;
        ttv = 0.1f * fmaxf(density, 1e-10f);
    } else {
        ttv = 0.01f;  // TEMP * TAU0
    }
    float xm = bm / ttv;
    float z = 0.f;
    for (int q = 0; q < 16; ++q) {
        float4 x = r4[lane + 64 * q];
        z += expf(x.x / ttv - xm) + expf(x.y / ttv - xm) +
             expf(x.z / ttv - xm) + expf(x.w / ttv - xm);
    }
    float zz = wsum(z);
    if (lane == 0) {
        tt[bp] = ttv;
        xmax[bp] = xm;
        Zr[bp] = zz;
    }
}

// ---- wide argmax: grid BB*16 blocks, 256 thr; each wave owns one 64-chunk.
// EXACT round-9 weight formula — the per-(n,p) comparison expression
// expf(s/tt-xm)/Z must not be reordered (round-10 lesson). Emits sidx/swv
// plus per-chunk per-p counts (ballot), all to global.
__global__ __launch_bounds__(256) void karg(const float* __restrict__ sim,
                                            const float* __restrict__ tt,
                                            const float* __restrict__ xmax,
                                            const float* __restrict__ Zr,
                                            unsigned char* __restrict__ sidxg,
                                            float* __restrict__ swvg,
                                            int* __restrict__ cntcg) {
    __shared__ float ttl[PP], xml[PP], zrl[PP];
    int bid = blockIdx.x;
    int b = bid >> 4, q = bid & 15;
    int tid = threadIdx.x;
    int wv = tid >> 6, lane = tid & 63;
    if (tid < PP) {
        ttl[tid] = tt[b * PP + tid];
        xml[tid] = xmax[b * PP + tid];
        zrl[tid] = Zr[b * PP + tid];
    }
    __syncthreads();
    const float* sb = sim + (size_t)(b * PP) * NN;
    int c = q * 4 + wv;
    int n = c * 64 + lane;
    float best = -1.f;
    int bi = 0;
#pragma unroll
    for (int p = 0; p < PP; ++p) {
        float s = sb[(size_t)p * NN + n];
        float wgt = expf(s / ttl[p] - xml[p]) / zrl[p];
        if (wgt > best) { best = wgt; bi = p; }
    }
    sidxg[(size_t)b * NN + n] = (unsigned char)bi;
    swvg[(size_t)b * NN + n] = best;
#pragma unroll
    for (int p = 0; p < PP; ++p) {
        unsigned long long bal = __ballot(bi == p);
        if (lane == p) cntcg[((size_t)b * 64 + c) * PP + p] = __popcll(bal);
    }
}

// ---- prefix: per-p prefix over chunks + exclusive prefix over p ----------
// grid BB, 64 threads (first 32 active). Loop orders instruction-identical
// to round 16's kassign phase 3 -> bit-identical cbase/cnt/offs.
__global__ __launch_bounds__(64) void kprefix(const int* __restrict__ cntcg,
                                              int* __restrict__ cbase,
                                              int* __restrict__ cnt,
                                              int* __restrict__ offs) {
    __shared__ int totl[PP];
    int b = blockIdx.x;
    int p = threadIdx.x;
    if (p < PP) {
        int run = 0;
        for (int c = 0; c < 64; ++c) {
            size_t idx = ((size_t)b * 64 + c) * PP + p;
            int t_ = cntcg[idx];
            cbase[idx] = run;
            run += t_;
        }
        totl[p] = run;
        cnt[b * PP + p] = run;
    }
    __syncthreads();
    if (p == 0) {
        int s = 0;
        for (int pp = 0; pp < PP; ++pp) {
            offs[b * PP + pp] = s;
            s += totl[pp];
        }
    }
}

// ---- wide scatter: grid BB*16 blocks, 256 thr; wave = one 64-chunk -------
// Ballot/rank sequence instruction-identical to round 16's phase 4
// -> bit-identical sortn/sortw.
__global__ __launch_bounds__(256) void kscatter(const unsigned char* __restrict__ sidxg,
                                                const float* __restrict__ swvg,
                                                const int* __restrict__ cbase,
                                                const int* __restrict__ offs,
                                                int* __restrict__ sortn,
                                                float* __restrict__ sortw) {
    __shared__ int offp[PP];
    __shared__ int cb[4][PP];
    int bid = blockIdx.x;
    int b = bid >> 4, q = bid & 15;
    int tid = threadIdx.x;
    int wv = tid >> 6, lane = tid & 63;
    if (tid < PP) offp[tid] = offs[b * PP + tid];
    int c = q * 4 + wv;
    if (lane < PP) cb[wv][lane] = cbase[((size_t)b * 64 + c) * PP + lane];
    __syncthreads();
    int n = c * 64 + lane;
    int bi = sidxg[(size_t)b * NN + n];
    float wgt = swvg[(size_t)b * NN + n];
    unsigned long long below = (1ull << lane) - 1ull;
#pragma unroll
    for (int p = 0; p < PP; ++p) {
        unsigned long long bal = __ballot(bi == p);
        if (bi == p) {
            int rank = __popcll(bal & below);
            int pos = offp[p] + cb[wv][p] + rank;
            sortn[(size_t)b * NN + pos] = (p << 12) | n;
            sortw[(size_t)b * NN + pos] = wgt;
        }
    }
}

// ---- update: 64-row window, float4 gather with 4-deep register prefetch --
#define UPD_STEP(FREG, JIDX, NXT)                                          \
    {                                                                      \
        int e = sn[JIDX];                                                  \
        int p = e >> 12;                                                   \
        float wv = sw[JIDX];                                               \
        float4 f = FREG;                                                   \
        if ((NXT) < WROWS) FREG = fb[(size_t)(sn[NXT] & 0xFFF) * 192 + t]; \
        if (p != curp) {                                                   \
            float4 o = {ax, ay, az, aw};                                   \
            pw[(size_t)curp * 192 + t] = o;                                \
            ax = ay = az = aw = 0.f;                                       \
            curp = p;                                                      \
        }                                                                  \
        ax = fmaf(wv, f.x, ax);                                            \
        ay = fmaf(wv, f.y, ay);                                            \
        az = fmaf(wv, f.z, az);                                            \
        aw = fmaf(wv, f.w, aw);                                            \
    }

__global__ __launch_bounds__(192) void kupdate(const float* __restrict__ feats,
                                               const int* __restrict__ sortn,
                                               const float* __restrict__ sortw,
                                               float* __restrict__ part) {
    __shared__ int sn[WROWS];
    __shared__ float sw[WROWS];
    int win = blockIdx.x & (NWIN - 1);
    int b = blockIdx.x >> 6;
    int t = threadIdx.x;
    if (t < WROWS) {
        sn[t] = sortn[b * NN + win * WROWS + t];
        sw[t] = sortw[b * NN + win * WROWS + t];
    }
    __syncthreads();
    const float4* fb = (const float4*)(feats + (size_t)b * NN * DD);
    float4* pw = (float4*)(part + (size_t)(b * NWIN + win) * PP * DD);
    float ax = 0.f, ay = 0.f, az = 0.f, aw = 0.f;
    int curp = sn[0] >> 12;
    float4 fp0 = fb[(size_t)(sn[0] & 0xFFF) * 192 + t];
    float4 fp1 = fb[(size_t)(sn[1] & 0xFFF) * 192 + t];
    float4 fp2 = fb[(size_t)(sn[2] & 0xFFF) * 192 + t];
    float4 fp3 = fb[(size_t)(sn[3] & 0xFFF) * 192 + t];
    for (int jj = 0; jj < WROWS; jj += 4) {
        UPD_STEP(fp0, jj + 0, jj + 4);
        UPD_STEP(fp1, jj + 1, jj + 5);
        UPD_STEP(fp2, jj + 2, jj + 6);
        UPD_STEP(fp3, jj + 3, jj + 7);
    }
    float4 o = {ax, ay, az, aw};
    pw[(size_t)curp * 192 + t] = o;
}

// ---- reduce window partials -> prototypes (+ final out) ------------------
__global__ __launch_bounds__(192) void kreduce(const float* __restrict__ part,
                                               const int* __restrict__ offs,
                                               const int* __restrict__ cnt,
                                               float* __restrict__ prot,
                                               float* __restrict__ outp) {
    int bp = blockIdx.x;
    int b = bp >> 5, p = bp & 31;
    int t = threadIdx.x;
    float4 s = {0.f, 0.f, 0.f, 0.f};
    int c = cnt[bp];
    if (c > 0) {
        int j0 = offs[bp];
        int w0 = j0 >> 6, w1 = (j0 + c - 1) >> 6;
        const float4* pr = (const float4*)(part);
        for (int w = w0; w <= w1; ++w) {
            float4 v = pr[(size_t)((b * NWIN + w) * PP + p) * 192 + t];
            s.x += v.x; s.y += v.y; s.z += v.z; s.w += v.w;
        }
    }
    ((float4*)(prot + (size_t)bp * DD))[t] = s;
    if (outp) ((float4*)(outp + (size_t)bp * DD))[t] = s;
}

extern "C" void kernel_launch(void* const* d_in, const int* in_sizes, int n_in,
                              void* d_out, int out_size, void* d_ws, size_t ws_size,
                              hipStream_t stream) {
    const float* protIn = (const float*)d_in[0];
    const float* feats = (const float*)d_in[1];
    const float* forg = (const float*)d_in[2];
    float* out = (float*)d_out;

    char* w = (char*)d_ws;
    auto alloc = [&](size_t bytes) {
        char* p = w;
        w += (bytes + 255) & ~(size_t)255;
        return p;
    };
    float* sim = (float*)alloc((size_t)BB * PP * NN * 4);
    float* prot = (float*)alloc((size_t)BB * PP * DD * 4);
    float* part = (float*)alloc((size_t)BB * NWIN * PP * DD * 4);
    float* ttb = (float*)alloc(BB * PP * 4);
    float* xmaxb = (float*)alloc(BB * PP * 4);
    float* Zrb = (float*)alloc(BB * PP * 4);
    unsigned char* sidxg = (unsigned char*)alloc((size_t)BB * NN);
    float* swvg = (float*)alloc((size_t)BB * NN * 4);
    int* cntcg = (int*)alloc((size_t)BB * 64 * PP * 4);
    int* cbase = (int*)alloc((size_t)BB * 64 * PP * 4);
    int* sortn = (int*)alloc((size_t)BB * NN * 4);
    float* sortw = (float*)alloc((size_t)BB * NN * 4);
    int* cnt = (int*)alloc(BB * PP * 4);
    int* offs = (int*)alloc(BB * PP * 4);

    for (int t = 0; t < 5; ++t) {
        ksim<<<BB * SNT, 256, 0, stream>>>(t == 0 ? protIn : prot, feats,
                                           (size_t)NN * DD, sim);
        kstats<<<BB * PP, 64, 0, stream>>>(sim, sortn, cnt, offs, ttb, xmaxb, Zrb,
                                           t > 0 ? 1 : 0);
        karg<<<BB * 16, 256, 0, stream>>>(sim, ttb, xmaxb, Zrb, sidxg, swvg, cntcg);
        kprefix<<<BB, 64, 0, stream>>>(cntcg, cbase, cnt, offs);
        kscatter<<<BB * 16, 256, 0, stream>>>(sidxg, swvg, cbase, offs, sortn, sortw);
        kupdate<<<BB * NWIN, 192, 0, stream>>>(feats, sortn, sortw, part);
        kreduce<<<BB * PP, 192, 0, stream>>>(part, offs, cnt, prot,
                                             (t == 4) ? out : nullptr);
    }
    // final similarity against feats_org (broadcast fsb=0) -> second output
    ksim<<<BB * SNT, 256, 0, stream>>>(prot, forg, (size_t)0,
                                       out + (size_t)BB * PP * DD);
}